// Round 1
// baseline (2147.906 us; speedup 1.0000x reference)
//
#include <hip/hip_runtime.h>
#include <hip/hip_bf16.h>
#include <math.h>

// Problem constants (B=1 fixed)
#define T_SEQ 2048
#define DMODEL 2048
#define NHQ 16
#define NHK 8
#define HDIM 128
#define NL 4
#define ATT_SCALE 0.08838834764831845f  // 1/sqrt(128)

// ---------------------------------------------------------------------------
// fp32 tiled GEMM: C[M,N] = A[M,K] * B[K,N]. 128x128 block tile, 16x16 threads,
// 8x8 outputs/thread split as {ty*4+i, 64+ty*4+i} x {tx*4+j, 64+tx*4+j} so all
// LDS reads are float4 with <=2-way bank aliasing (free per m136).
// ---------------------------------------------------------------------------
#define TBM 128
#define TBN 128
#define TKT 16

__global__ __launch_bounds__(256) void gemm_f32(
    const float* __restrict__ A, const float* __restrict__ B, float* __restrict__ C,
    int M, int N, int K)
{
    __shared__ float As[TKT][TBM + 4];
    __shared__ float Bs[TKT][TBN + 4];
    const int tx = threadIdx.x;          // 0..15
    const int ty = threadIdx.y;          // 0..15
    const int tid = ty * 16 + tx;
    const int bm = blockIdx.y * TBM;
    const int bn = blockIdx.x * TBN;

    float acc[8][8] = {{0.f}};

    for (int k0 = 0; k0 < K; k0 += TKT) {
        // A tile: 128 rows x 16 k = 512 float4, 2 per thread
        #pragma unroll
        for (int it = 0; it < 2; ++it) {
            int fi = tid + it * 256;
            int m  = fi >> 2;            // 0..127
            int kk = (fi & 3) * 4;       // 0,4,8,12
            float4 a = *(const float4*)&A[(size_t)(bm + m) * K + k0 + kk];
            As[kk + 0][m] = a.x; As[kk + 1][m] = a.y;
            As[kk + 2][m] = a.z; As[kk + 3][m] = a.w;
        }
        // B tile: 16 k x 128 n = 512 float4, 2 per thread
        #pragma unroll
        for (int it = 0; it < 2; ++it) {
            int fi = tid + it * 256;
            int kk = fi >> 5;            // 0..15
            int n  = (fi & 31) * 4;      // 0..124
            *(float4*)&Bs[kk][n] = *(const float4*)&B[(size_t)(k0 + kk) * N + bn + n];
        }
        __syncthreads();
        #pragma unroll
        for (int kk = 0; kk < TKT; ++kk) {
            float av[8], bv[8];
            *(float4*)&av[0] = *(const float4*)&As[kk][ty * 4];
            *(float4*)&av[4] = *(const float4*)&As[kk][64 + ty * 4];
            *(float4*)&bv[0] = *(const float4*)&Bs[kk][tx * 4];
            *(float4*)&bv[4] = *(const float4*)&Bs[kk][64 + tx * 4];
            #pragma unroll
            for (int i = 0; i < 8; ++i)
                #pragma unroll
                for (int j = 0; j < 8; ++j)
                    acc[i][j] = fmaf(av[i], bv[j], acc[i][j]);
        }
        __syncthreads();
    }
    #pragma unroll
    for (int hi = 0; hi < 2; ++hi)
        #pragma unroll
        for (int i = 0; i < 4; ++i) {
            size_t crow = (size_t)(bm + hi * 64 + ty * 4 + i) * N + bn;
            #pragma unroll
            for (int hj = 0; hj < 2; ++hj) {
                float4 r = make_float4(acc[hi * 4 + i][hj * 4 + 0], acc[hi * 4 + i][hj * 4 + 1],
                                       acc[hi * 4 + i][hj * 4 + 2], acc[hi * 4 + i][hj * 4 + 3]);
                *(float4*)&C[crow + hj * 64 + tx * 4] = r;
            }
        }
}

// ---------------------------------------------------------------------------
// In-place RoPE on P[T][H*128]. One thread per (t,h,d<64) pair.
// cos/sin tables duplicate halves: cos[t,d] == cos[t,d+64].
// ---------------------------------------------------------------------------
__global__ __launch_bounds__(256) void rope_f32(
    float* __restrict__ P, const float* __restrict__ cosT,
    const float* __restrict__ sinT, int H)
{
    int idx = blockIdx.x * 256 + threadIdx.x;  // T*H*64 threads total
    int d = idx & 63;
    int h = (idx >> 6) % H;
    int t = idx / (64 * H);
    float c = cosT[t * HDIM + d];
    float s = sinT[t * HDIM + d];
    float* row = P + (size_t)t * (H * HDIM) + h * HDIM;
    float x0 = row[d], x1 = row[d + 64];
    row[d]      = x0 * c - x1 * s;   // rotate_half: first half = -x[d+64]
    row[d + 64] = x1 * c + x0 * s;   // second half = +x[d]
}

// ---------------------------------------------------------------------------
// Fused causal flash attention + 4 depth slots (joint softmax).
// Block = 256 threads = 64 query rows x 4 dim-parts (32 dims each), one head.
// K/V tiles (32 keys x 128) staged in LDS as [32][4][36] so the 4 p-lanes of a
// row-group read distinct banks (conflict-free ds_read_b128).
// ---------------------------------------------------------------------------
__global__ __launch_bounds__(256) void attn_f32(
    const float* __restrict__ Q, const float* __restrict__ Kg, const float* __restrict__ Vg,
    const float* __restrict__ Dk, const float* __restrict__ Dv, float* __restrict__ O)
{
    __shared__ float Ks[32][4][36];
    __shared__ float Vs[32][4][36];
    const int hq = blockIdx.y;
    const int hk = hq >> 1;                  // GQA=2 repeat_interleave
    const int q0 = blockIdx.x * 64;
    const int tid = threadIdx.x;
    const int r = tid >> 2;                  // query row in tile (0..63)
    const int p = tid & 3;                   // dim part (owns 32 dims)
    const int t = q0 + r;

    float q[32], acc[32];
    const float* qrow = Q + (size_t)t * DMODEL + hq * HDIM + p * 32;
    #pragma unroll
    for (int i = 0; i < 32; i += 4) {
        float4 v = *(const float4*)(qrow + i);
        q[i] = v.x; q[i + 1] = v.y; q[i + 2] = v.z; q[i + 3] = v.w;
        acc[i] = acc[i + 1] = acc[i + 2] = acc[i + 3] = 0.f;
    }
    float m = -INFINITY, s = 0.f;

    const int jend = q0 + 64;                // causal: keys up to q0+63
    for (int j0 = 0; j0 < jend; j0 += 32) {
        // cooperative K/V tile load: 1024 float4 each, 4 per thread
        #pragma unroll
        for (int it = 0; it < 4; ++it) {
            int fi  = tid + it * 256;
            int row = fi >> 5;
            int col = (fi & 31) * 4;
            int pp  = col >> 5;
            int ii  = col & 31;
            size_t g = (size_t)(j0 + row) * (NHK * HDIM) + hk * HDIM + col;
            *(float4*)&Ks[row][pp][ii] = *(const float4*)&Kg[g];
            *(float4*)&Vs[row][pp][ii] = *(const float4*)&Vg[g];
        }
        __syncthreads();

        float lg[32];
        #pragma unroll
        for (int j = 0; j < 32; ++j) {
            const float* krow = &Ks[j][p][0];
            float d = 0.f;
            #pragma unroll
            for (int i = 0; i < 32; ++i) d = fmaf(q[i], krow[i], d);
            d += __shfl_xor(d, 1);
            d += __shfl_xor(d, 2);
            lg[j] = (j0 + j <= t) ? d * ATT_SCALE : -INFINITY;
        }
        float tmax = m;
        #pragma unroll
        for (int j = 0; j < 32; ++j) tmax = fmaxf(tmax, lg[j]);
        float rescale = __expf(m - tmax);    // m=-inf first tile -> 0
        s *= rescale;
        #pragma unroll
        for (int i = 0; i < 32; ++i) acc[i] *= rescale;
        m = tmax;
        #pragma unroll
        for (int j = 0; j < 32; ++j) {
            float pe = __expf(lg[j] - m);    // masked -> exp(-inf)=0
            s += pe;
            const float* vrow = &Vs[j][p][0];
            #pragma unroll
            for (int i = 0; i < 32; ++i) acc[i] = fmaf(pe, vrow[i], acc[i]);
        }
        __syncthreads();
    }

    // depth slots: keys/values at this query's own position, L=4
    {
        float lg[NL];
        #pragma unroll
        for (int l = 0; l < NL; ++l) {
            const float* kd = Dk + (((size_t)l * NHK + hk) * T_SEQ + t) * HDIM + p * 32;
            float d = 0.f;
            #pragma unroll
            for (int i = 0; i < 32; ++i) d = fmaf(q[i], kd[i], d);
            d += __shfl_xor(d, 1);
            d += __shfl_xor(d, 2);
            lg[l] = d * ATT_SCALE;
        }
        float tmax = m;
        #pragma unroll
        for (int l = 0; l < NL; ++l) tmax = fmaxf(tmax, lg[l]);
        float rescale = __expf(m - tmax);
        s *= rescale;
        #pragma unroll
        for (int i = 0; i < 32; ++i) acc[i] *= rescale;
        m = tmax;
        #pragma unroll
        for (int l = 0; l < NL; ++l) {
            float pe = __expf(lg[l] - m);
            s += pe;
            const float* vd = Dv + (((size_t)l * NHK + hk) * T_SEQ + t) * HDIM + p * 32;
            #pragma unroll
            for (int i = 0; i < 32; ++i) acc[i] = fmaf(pe, vd[i], acc[i]);
        }
    }

    float inv = 1.f / s;
    float* orow = O + (size_t)t * DMODEL + hq * HDIM + p * 32;
    #pragma unroll
    for (int i = 0; i < 32; i += 4) {
        float4 v = make_float4(acc[i] * inv, acc[i + 1] * inv, acc[i + 2] * inv, acc[i + 3] * inv);
        *(float4*)(orow + i) = v;
    }
}

// ---------------------------------------------------------------------------
extern "C" void kernel_launch(void* const* d_in, const int* in_sizes, int n_in,
                              void* d_out, int out_size, void* d_ws, size_t ws_size,
                              hipStream_t stream) {
    const float* x   = (const float*)d_in[0];   // [1,2048,2048]
    const float* dk  = (const float*)d_in[1];   // [4,1,8,2048,128]
    const float* dv  = (const float*)d_in[2];   // [4,1,8,2048,128]
    const float* cosT = (const float*)d_in[3];  // [1,1,2048,128]
    const float* sinT = (const float*)d_in[4];
    const float* Wq  = (const float*)d_in[5];   // [2048,2048]
    const float* Wk  = (const float*)d_in[6];   // [2048,1024]
    const float* Wv  = (const float*)d_in[7];   // [2048,1024]
    const float* Wo  = (const float*)d_in[8];   // [2048,2048]
    float* out = (float*)d_out;                 // [1,2048,2048]

    // workspace: Q(4M) K(2M) V(2M) AO(4M) floats = 48 MB
    float* Q  = (float*)d_ws;
    float* K  = Q + (size_t)4 * 1024 * 1024;
    float* V  = K + (size_t)2 * 1024 * 1024;
    float* AO = V + (size_t)2 * 1024 * 1024;

    dim3 blk(16, 16);
    // projections
    gemm_f32<<<dim3(DMODEL / TBN, T_SEQ / TBM), blk, 0, stream>>>(x, Wq, Q, T_SEQ, DMODEL, DMODEL);
    gemm_f32<<<dim3((NHK * HDIM) / TBN, T_SEQ / TBM), blk, 0, stream>>>(x, Wk, K, T_SEQ, NHK * HDIM, DMODEL);
    gemm_f32<<<dim3((NHK * HDIM) / TBN, T_SEQ / TBM), blk, 0, stream>>>(x, Wv, V, T_SEQ, NHK * HDIM, DMODEL);
    // RoPE on Q and K (in-place; recomputed from x every call -> deterministic)
    rope_f32<<<dim3(T_SEQ * NHQ * 64 / 256), 256, 0, stream>>>(Q, cosT, sinT, NHQ);
    rope_f32<<<dim3(T_SEQ * NHK * 64 / 256), 256, 0, stream>>>(K, cosT, sinT, NHK);
    // fused causal + depth attention
    attn_f32<<<dim3(T_SEQ / 64, NHQ), 256, 0, stream>>>(Q, K, V, dk, dv, AO);
    // output projection
    gemm_f32<<<dim3(DMODEL / TBN, T_SEQ / TBM), blk, 0, stream>>>(AO, Wo, out, T_SEQ, DMODEL, DMODEL);
}

// Round 2
// 1094.301 us; speedup vs baseline: 1.9628x; 1.9628x over previous
//
#include <hip/hip_runtime.h>
#include <hip/hip_bf16.h>
#include <math.h>

#define T_SEQ 2048
#define DMODEL 2048
#define NHQ 16
#define NHK 8
#define HDIM 128
#define NL 4
#define ATT_SCALE 0.08838834764831845f  // 1/sqrt(128)

typedef __attribute__((ext_vector_type(8))) short bf16x8;
typedef __attribute__((ext_vector_type(4))) float f32x4;

__device__ __forceinline__ float bf2f(short u) {
    union { float f; unsigned int i; } x;
    x.i = ((unsigned int)(unsigned short)u) << 16;
    return x.f;
}
__device__ __forceinline__ unsigned short f2bf(float f) {
    __hip_bfloat16 h = __float2bfloat16(f);
    return *reinterpret_cast<unsigned short*>(&h);
}
__device__ __forceinline__ void gload16(const void* g, void* l) {
    __builtin_amdgcn_global_load_lds(
        (const __attribute__((address_space(1))) void*)g,
        (__attribute__((address_space(3))) void*)l, 16, 0, 0);
}

// ---------------------------------------------------------------------------
// fp32 tiled GEMM, 128x128 tile. mode 0: fp32 C. mode 1: bf16 C row-major.
// mode 2: bf16 C transposed [N][M] (for V -> Vt so PV B-frags read row-major).
// ---------------------------------------------------------------------------
#define TBM 128
#define TBN 128
#define TKT 16

__global__ __launch_bounds__(256) void gemm_f32(
    const float* __restrict__ A, const float* __restrict__ B,
    float* __restrict__ Cf, unsigned short* __restrict__ Cb, int mode,
    int M, int N, int K)
{
    __shared__ float As[TKT][TBM + 4];
    __shared__ float Bs[TKT][TBN + 4];
    const int tx = threadIdx.x, ty = threadIdx.y;
    const int tid = ty * 16 + tx;
    const int bm = blockIdx.y * TBM;
    const int bn = blockIdx.x * TBN;

    float acc[8][8] = {{0.f}};

    for (int k0 = 0; k0 < K; k0 += TKT) {
        #pragma unroll
        for (int it = 0; it < 2; ++it) {
            int fi = tid + it * 256;
            int m  = fi >> 2;
            int kk = (fi & 3) * 4;
            float4 a = *(const float4*)&A[(size_t)(bm + m) * K + k0 + kk];
            As[kk + 0][m] = a.x; As[kk + 1][m] = a.y;
            As[kk + 2][m] = a.z; As[kk + 3][m] = a.w;
        }
        #pragma unroll
        for (int it = 0; it < 2; ++it) {
            int fi = tid + it * 256;
            int kk = fi >> 5;
            int n  = (fi & 31) * 4;
            *(float4*)&Bs[kk][n] = *(const float4*)&B[(size_t)(k0 + kk) * N + bn + n];
        }
        __syncthreads();
        #pragma unroll
        for (int kk = 0; kk < TKT; ++kk) {
            float av[8], bv[8];
            *(float4*)&av[0] = *(const float4*)&As[kk][ty * 4];
            *(float4*)&av[4] = *(const float4*)&As[kk][64 + ty * 4];
            *(float4*)&bv[0] = *(const float4*)&Bs[kk][tx * 4];
            *(float4*)&bv[4] = *(const float4*)&Bs[kk][64 + tx * 4];
            #pragma unroll
            for (int i = 0; i < 8; ++i)
                #pragma unroll
                for (int j = 0; j < 8; ++j)
                    acc[i][j] = fmaf(av[i], bv[j], acc[i][j]);
        }
        __syncthreads();
    }

    if (mode == 0) {
        #pragma unroll
        for (int hi = 0; hi < 2; ++hi)
            #pragma unroll
            for (int i = 0; i < 4; ++i) {
                size_t crow = (size_t)(bm + hi * 64 + ty * 4 + i) * N + bn;
                #pragma unroll
                for (int hj = 0; hj < 2; ++hj) {
                    float4 r = make_float4(acc[hi*4+i][hj*4+0], acc[hi*4+i][hj*4+1],
                                           acc[hi*4+i][hj*4+2], acc[hi*4+i][hj*4+3]);
                    *(float4*)&Cf[crow + hj * 64 + tx * 4] = r;
                }
            }
    } else if (mode == 1) {
        #pragma unroll
        for (int hi = 0; hi < 2; ++hi)
            #pragma unroll
            for (int i = 0; i < 4; ++i) {
                size_t crow = (size_t)(bm + hi * 64 + ty * 4 + i) * N + bn;
                #pragma unroll
                for (int hj = 0; hj < 2; ++hj) {
                    ushort4 r;
                    r.x = f2bf(acc[hi*4+i][hj*4+0]); r.y = f2bf(acc[hi*4+i][hj*4+1]);
                    r.z = f2bf(acc[hi*4+i][hj*4+2]); r.w = f2bf(acc[hi*4+i][hj*4+3]);
                    *(ushort4*)&Cb[crow + hj * 64 + tx * 4] = r;
                }
            }
    } else {
        // transposed bf16: Cb[n*M + m]
        #pragma unroll
        for (int hj = 0; hj < 2; ++hj)
            #pragma unroll
            for (int j = 0; j < 4; ++j) {
                int n = bn + hj * 64 + tx * 4 + j;
                #pragma unroll
                for (int hi = 0; hi < 2; ++hi) {
                    int t0 = bm + hi * 64 + ty * 4;
                    ushort4 r;
                    r.x = f2bf(acc[hi*4+0][hj*4+j]); r.y = f2bf(acc[hi*4+1][hj*4+j]);
                    r.z = f2bf(acc[hi*4+2][hj*4+j]); r.w = f2bf(acc[hi*4+3][hj*4+j]);
                    *(ushort4*)&Cb[(size_t)n * M + t0] = r;
                }
            }
    }
}

// ---------------------------------------------------------------------------
// In-place RoPE on bf16 P[T][H*128].
// ---------------------------------------------------------------------------
__global__ __launch_bounds__(256) void rope_bf16(
    unsigned short* __restrict__ P, const float* __restrict__ cosT,
    const float* __restrict__ sinT, int H)
{
    int idx = blockIdx.x * 256 + threadIdx.x;  // T*H*64 threads
    int d = idx & 63;
    int h = (idx >> 6) % H;
    int t = idx / (64 * H);
    float c = cosT[t * HDIM + d];
    float s = sinT[t * HDIM + d];
    unsigned short* row = P + (size_t)t * (H * HDIM) + h * HDIM;
    float x0 = bf2f((short)row[d]), x1 = bf2f((short)row[d + 64]);
    row[d]      = f2bf(x0 * c - x1 * s);
    row[d + 64] = f2bf(x1 * c + x0 * s);
}

// ---------------------------------------------------------------------------
// MFMA flash attention + 4 depth slots. Block = 4 waves, 64 q-rows, 1 head.
// Wave w owns rows [q0+16w, +16). KV tiles of 32 keys staged in LDS bf16 via
// global_load_lds(16B) with pre-swizzled global source (rule #21):
//   K tile  [32][128]: chunk ^= (row&7)        (G4 XOR swizzle)
//   Vt tile [128][32]: chunk ^= (d ^ d>>2)&3
// S in C-layout (col=lane&15=key, row=(lane>>4)*4+reg), online softmax via
// 16-lane shfl_xor reduce; P -> per-wave swizzled LDS -> A-frag for PV.
// ---------------------------------------------------------------------------
__global__ __launch_bounds__(256) void attn_mfma(
    const unsigned short* __restrict__ Qb, const unsigned short* __restrict__ Kb,
    const unsigned short* __restrict__ Vt,
    const float* __restrict__ Dk, const float* __restrict__ Dv,
    float* __restrict__ AO)
{
    __shared__ char lds[8192 + 8192 + 4096];
    char* Ks = lds;
    char* Vs = lds + 8192;
    char* Ps = lds + 16384;

    const int hq = blockIdx.y, hk = hq >> 1;
    const int q0 = ((int)gridDim.x - 1 - (int)blockIdx.x) * 64;  // long blocks first
    const int tid = threadIdx.x;
    const int wv = tid >> 6, lane = tid & 63;
    const int l15 = lane & 15, lg = lane >> 4;
    const size_t DSTRIDE = (size_t)NHK * T_SEQ * HDIM;

    // Q A-fragments (row = lane&15, k = lg*8 + j per 32-chunk)
    const int trow_a = q0 + wv * 16 + l15;
    bf16x8 qf[4];
    {
        const unsigned short* qrow = Qb + (size_t)trow_a * DMODEL + hq * HDIM;
        #pragma unroll
        for (int c = 0; c < 4; ++c)
            qf[c] = *(const bf16x8*)(qrow + c * 32 + lg * 8);
    }

    f32x4 oacc[8];
    #pragma unroll
    for (int dt = 0; dt < 8; ++dt) oacc[dt] = (f32x4){0.f, 0.f, 0.f, 0.f};
    float mrun[4], lrun[4];
    #pragma unroll
    for (int r = 0; r < 4; ++r) { mrun[r] = -1e30f; lrun[r] = 0.f; }

    const int trow_c = q0 + wv * 16 + lg * 4;   // + reg
    const int pswz = (l15 ^ (l15 >> 2)) & 3;    // P/V read swizzle for this lane

    const int jend = q0 + 64;
    for (int j0 = 0; j0 < jend; j0 += 32) {
        // ---- stage K[j0..j0+31][0..127] and Vt[0..127][j0..j0+31] (bf16) ----
        #pragma unroll
        for (int it = 0; it < 2; ++it) {
            int Pb = wv * 2048 + it * 1024 + lane * 16;
            int row = Pb >> 8;
            int cl  = ((Pb >> 4) & 15) ^ (row & 7);
            gload16((const char*)Kb + (size_t)(j0 + row) * (NHK * HDIM * 2) + hk * 256 + cl * 16,
                    Ks + wv * 2048 + it * 1024);
            int d  = Pb >> 6;
            int cv = ((Pb >> 4) & 3) ^ ((d ^ (d >> 2)) & 3);
            gload16((const char*)Vt + (size_t)(hk * 128 + d) * (T_SEQ * 2) + (size_t)j0 * 2 + cv * 16,
                    Vs + wv * 2048 + it * 1024);
        }
        __syncthreads();

        if (j0 <= q0 + wv * 16 + 15) {   // skip fully-masked tiles for this wave
            // ---- S = Q K^T : 2 key-subtiles x 4 k-chunks ----
            f32x4 sa[2];
            #pragma unroll
            for (int s = 0; s < 2; ++s) {
                sa[s] = (f32x4){0.f, 0.f, 0.f, 0.f};
                int row = s * 16 + l15;
                #pragma unroll
                for (int c = 0; c < 4; ++c) {
                    int ch = (c * 4 + lg) ^ (row & 7);
                    bf16x8 kf = *(const bf16x8*)(Ks + row * 256 + ch * 16);
                    sa[s] = __builtin_amdgcn_mfma_f32_16x16x32_bf16(qf[c], kf, sa[s], 0, 0, 0);
                }
            }
            // ---- mask + online softmax ----
            float p[2][4];
            #pragma unroll
            for (int s = 0; s < 2; ++s)
                #pragma unroll
                for (int r = 0; r < 4; ++r) {
                    int key = j0 + s * 16 + l15;
                    float v = sa[s][r] * ATT_SCALE;
                    p[s][r] = (key <= trow_c + r) ? v : -1e30f;
                }
            float rs[4];
            #pragma unroll
            for (int r = 0; r < 4; ++r) {
                float v = fmaxf(p[0][r], p[1][r]);
                v = fmaxf(v, __shfl_xor(v, 1));
                v = fmaxf(v, __shfl_xor(v, 2));
                v = fmaxf(v, __shfl_xor(v, 4));
                v = fmaxf(v, __shfl_xor(v, 8));
                float mn = fmaxf(mrun[r], v);
                rs[r] = __expf(mrun[r] - mn);
                mrun[r] = mn;
            }
            #pragma unroll
            for (int s = 0; s < 2; ++s)
                #pragma unroll
                for (int r = 0; r < 4; ++r)
                    p[s][r] = __expf(p[s][r] - mrun[r]);
            #pragma unroll
            for (int r = 0; r < 4; ++r) {
                float sum = p[0][r] + p[1][r];
                sum += __shfl_xor(sum, 1);
                sum += __shfl_xor(sum, 2);
                sum += __shfl_xor(sum, 4);
                sum += __shfl_xor(sum, 8);
                lrun[r] = lrun[r] * rs[r] + sum;
                #pragma unroll
                for (int dt = 0; dt < 8; ++dt) oacc[dt][r] *= rs[r];
            }
            // ---- P -> per-wave LDS (transpose to A-frag layout), bf16 ----
            char* pw = Ps + wv * 1024;
            #pragma unroll
            for (int s = 0; s < 2; ++s)
                #pragma unroll
                for (int r = 0; r < 4; ++r) {
                    int row = lg * 4 + r;
                    int key = s * 16 + l15;
                    int ch  = (key >> 3) ^ (r ^ lg) ^ ((r ^ lg) & ~3);  // (row^(row>>2))&3 == (r^lg)&3
                    ch = (key >> 3) ^ ((r ^ lg) & 3);
                    *(unsigned short*)(pw + row * 64 + ch * 16 + (key & 7) * 2) = f2bf(p[s][r]);
                }
            asm volatile("" ::: "memory");  // keep writes before reads (in-order DS pipe)
            // ---- PV: O += P V ----
            {
                bf16x8 pa = *(const bf16x8*)(pw + l15 * 64 + (lg ^ pswz) * 16);
                #pragma unroll
                for (int dt = 0; dt < 8; ++dt) {
                    int d = dt * 16 + l15;
                    bf16x8 vf = *(const bf16x8*)(Vs + d * 64 + (lg ^ pswz) * 16);
                    oacc[dt] = __builtin_amdgcn_mfma_f32_16x16x32_bf16(pa, vf, oacc[dt], 0, 0, 0);
                }
            }
        }
        __syncthreads();
    }

    // ---- depth slots (per-query keys, VALU) ----
    float dl[NL];
    #pragma unroll
    for (int sl = 0; sl < NL; ++sl) {
        const float* kd = Dk + sl * DSTRIDE + ((size_t)hk * T_SEQ + trow_a) * HDIM;
        float acc = 0.f;
        #pragma unroll
        for (int c = 0; c < 4; ++c) {
            const float* kc = kd + c * 32 + lg * 8;
            #pragma unroll
            for (int j = 0; j < 8; ++j)
                acc = fmaf(bf2f(qf[c][j]), kc[j], acc);
        }
        acc += __shfl_xor(acc, 16);
        acc += __shfl_xor(acc, 32);
        dl[sl] = acc * ATT_SCALE;
    }
    #pragma unroll
    for (int r = 0; r < 4; ++r) {
        int src = trow_c + r - q0 - wv * 16;   // row index 0..15 -> lane holding it
        float d0 = __shfl(dl[0], src);
        float d1 = __shfl(dl[1], src);
        float d2 = __shfl(dl[2], src);
        float d3 = __shfl(dl[3], src);
        float vm = fmaxf(fmaxf(d0, d1), fmaxf(d2, d3));
        float mn = fmaxf(mrun[r], vm);
        float rs = __expf(mrun[r] - mn);
        float p0 = __expf(d0 - mn), p1 = __expf(d1 - mn);
        float p2 = __expf(d2 - mn), p3 = __expf(d3 - mn);
        lrun[r] = lrun[r] * rs + (p0 + p1 + p2 + p3);
        int t = trow_c + r;
        #pragma unroll
        for (int dt = 0; dt < 8; ++dt) {
            const float* vb = Dv + ((size_t)hk * T_SEQ + t) * HDIM + dt * 16 + l15;
            float o = oacc[dt][r] * rs;
            o = fmaf(p0, vb[0], o);
            o = fmaf(p1, vb[DSTRIDE], o);
            o = fmaf(p2, vb[2 * DSTRIDE], o);
            o = fmaf(p3, vb[3 * DSTRIDE], o);
            oacc[dt][r] = o;
        }
    }
    // ---- normalize + store ----
    #pragma unroll
    for (int r = 0; r < 4; ++r) {
        float inv = 1.f / lrun[r];
        float* orow = AO + (size_t)(trow_c + r) * DMODEL + hq * HDIM;
        #pragma unroll
        for (int dt = 0; dt < 8; ++dt)
            orow[dt * 16 + l15] = oacc[dt][r] * inv;
    }
}

// ---------------------------------------------------------------------------
extern "C" void kernel_launch(void* const* d_in, const int* in_sizes, int n_in,
                              void* d_out, int out_size, void* d_ws, size_t ws_size,
                              hipStream_t stream) {
    const float* x    = (const float*)d_in[0];
    const float* dk   = (const float*)d_in[1];
    const float* dv   = (const float*)d_in[2];
    const float* cosT = (const float*)d_in[3];
    const float* sinT = (const float*)d_in[4];
    const float* Wq   = (const float*)d_in[5];
    const float* Wk   = (const float*)d_in[6];
    const float* Wv   = (const float*)d_in[7];
    const float* Wo   = (const float*)d_in[8];
    float* out = (float*)d_out;

    // ws: Qb bf16 8MB | Kb bf16 4MB | Vt bf16 4MB | AO f32 16MB  (32MB total)
    unsigned short* Qb = (unsigned short*)d_ws;
    unsigned short* Kb = Qb + (size_t)T_SEQ * DMODEL;
    unsigned short* Vt = Kb + (size_t)T_SEQ * 1024;
    float* AO = (float*)(Vt + (size_t)1024 * T_SEQ);

    dim3 blk(16, 16);
    gemm_f32<<<dim3(DMODEL / TBN, T_SEQ / TBM), blk, 0, stream>>>(
        x, Wq, nullptr, Qb, 1, T_SEQ, DMODEL, DMODEL);
    gemm_f32<<<dim3(1024 / TBN, T_SEQ / TBM), blk, 0, stream>>>(
        x, Wk, nullptr, Kb, 1, T_SEQ, 1024, DMODEL);
    gemm_f32<<<dim3(1024 / TBN, T_SEQ / TBM), blk, 0, stream>>>(
        x, Wv, nullptr, Vt, 2, T_SEQ, 1024, DMODEL);
    rope_bf16<<<dim3(T_SEQ * NHQ * 64 / 256), 256, 0, stream>>>(Qb, cosT, sinT, NHQ);
    rope_bf16<<<dim3(T_SEQ * NHK * 64 / 256), 256, 0, stream>>>(Kb, cosT, sinT, NHK);
    attn_mfma<<<dim3(T_SEQ / 64, NHQ), 256, 0, stream>>>(Qb, Kb, Vt, dk, dv, AO);
    gemm_f32<<<dim3(DMODEL / TBN, T_SEQ / TBM), blk, 0, stream>>>(
        AO, Wo, out, nullptr, 0, T_SEQ, DMODEL, DMODEL);
}

// Round 3
// 255.839 us; speedup vs baseline: 8.3955x; 4.2773x over previous
//
#include <hip/hip_runtime.h>
#include <hip/hip_bf16.h>
#include <math.h>

#define T_SEQ 2048
#define DMODEL 2048
#define NHQ 16
#define NHK 8
#define HDIM 128
#define NL 4
#define ATT_SCALE 0.08838834764831845f  // 1/sqrt(128)

typedef __attribute__((ext_vector_type(8))) short bf16x8;
typedef __attribute__((ext_vector_type(4))) float f32x4;

__device__ __forceinline__ float bf2f(short u) {
    union { float f; unsigned int i; } x;
    x.i = ((unsigned int)(unsigned short)u) << 16;
    return x.f;
}
__device__ __forceinline__ unsigned short f2bf(float f) {
    __hip_bfloat16 h = __float2bfloat16(f);
    return *reinterpret_cast<unsigned short*>(&h);
}
__device__ __forceinline__ void gload16(const void* g, void* l) {
    __builtin_amdgcn_global_load_lds(
        (const __attribute__((address_space(1))) void*)g,
        (__attribute__((address_space(3))) void*)l, 16, 0, 0);
}

// ---------------------------------------------------------------------------
// Cast fp32 -> bf16, 8 elems/thread.
// ---------------------------------------------------------------------------
__global__ __launch_bounds__(256) void cast_f32_bf16(
    const float* __restrict__ s, unsigned short* __restrict__ d)
{
    int i = blockIdx.x * 256 + threadIdx.x;
    float4 a = ((const float4*)s)[2 * i];
    float4 b = ((const float4*)s)[2 * i + 1];
    bf16x8 v;
    v[0] = (short)f2bf(a.x); v[1] = (short)f2bf(a.y);
    v[2] = (short)f2bf(a.z); v[3] = (short)f2bf(a.w);
    v[4] = (short)f2bf(b.x); v[5] = (short)f2bf(b.y);
    v[6] = (short)f2bf(b.z); v[7] = (short)f2bf(b.w);
    ((bf16x8*)d)[i] = v;
}

// ---------------------------------------------------------------------------
// Transpose-cast: src fp32 [Ksrc][Nsrc] row-major -> dst bf16 [Nsrc][Ksrc]
// at row offset dstOff (dst ld = Ksrc). 64x64 tile via LDS.
// ---------------------------------------------------------------------------
__global__ __launch_bounds__(256) void tcast(
    const float* __restrict__ src, unsigned short* __restrict__ dst,
    int Nsrc, int Ksrc, int dstOff)
{
    __shared__ float ls[64][65];
    const int k0 = blockIdx.x * 64, n0 = blockIdx.y * 64;
    const int tid = threadIdx.x;
    #pragma unroll
    for (int it = 0; it < 4; ++it) {
        int fi = tid + it * 256;      // 0..1023
        int r = fi >> 4;              // 0..63
        int c = (fi & 15) * 4;
        float4 v = *(const float4*)&src[(size_t)(k0 + r) * Nsrc + n0 + c];
        ls[r][c] = v.x; ls[r][c + 1] = v.y; ls[r][c + 2] = v.z; ls[r][c + 3] = v.w;
    }
    __syncthreads();
    int n = tid & 63, kc = tid >> 6;  // kc 0..3
    bf16x8 v0, v1;
    #pragma unroll
    for (int j = 0; j < 8; ++j) v0[j] = (short)f2bf(ls[kc * 16 + j][n]);
    #pragma unroll
    for (int j = 0; j < 8; ++j) v1[j] = (short)f2bf(ls[kc * 16 + 8 + j][n]);
    size_t drow = (size_t)(dstOff + n0 + n) * Ksrc + k0 + kc * 16;
    *(bf16x8*)&dst[drow] = v0;
    *(bf16x8*)&dst[drow + 8] = v1;
}

// ---------------------------------------------------------------------------
// bf16 MFMA GEMM, m97 structure: C[M,N] = A[M,K] * Bt[N,K]^T.
// 128x128 tile, BK=64, 4 waves (2x2), each wave 64x64 = 4x4 16x16 frags.
// LDS [128 rows][8 chunks of 16B] with chunk ^= row&7 swizzle, staged via
// global_load_lds(16B) from pre-swizzled source (rule #21).
// mode 0: f32 C row-major (ld 2048).
// mode 1: fused projection epilogue over N=4096:
//         n<2048 -> Cq bf16 [t][2048]; n<3072 -> Ck bf16 [t][1024];
//         else   -> Cv bf16 transposed [n-3072][2048].
// ---------------------------------------------------------------------------
__global__ __launch_bounds__(256) void gemm_bt(
    const unsigned short* __restrict__ A, const unsigned short* __restrict__ Bt,
    float* __restrict__ Cf, unsigned short* __restrict__ Cq,
    unsigned short* __restrict__ Ck, unsigned short* __restrict__ Cv,
    int mode, int K)
{
    __shared__ char As[16384];
    __shared__ char Bs[16384];
    const int tid = threadIdx.x;
    const int wv = tid >> 6, lane = tid & 63;
    const int l15 = lane & 15, lg = lane >> 4;
    const int wm = wv >> 1, wn = wv & 1;
    const int bm = blockIdx.y * 128, bn = blockIdx.x * 128;

    f32x4 acc[4][4];
    #pragma unroll
    for (int i = 0; i < 4; ++i)
        #pragma unroll
        for (int j = 0; j < 4; ++j)
            acc[i][j] = (f32x4){0.f, 0.f, 0.f, 0.f};

    for (int k0 = 0; k0 < K; k0 += 64) {
        #pragma unroll
        for (int it = 0; it < 4; ++it) {
            int o = it * 4096 + tid * 16;
            int row = o >> 7;
            int sch = ((o >> 4) & 7) ^ (row & 7);
            gload16((const char*)A + ((((size_t)(bm + row) * K) + k0 + sch * 8) << 1),
                    As + it * 4096 + wv * 1024);
            gload16((const char*)Bt + ((((size_t)(bn + row) * K) + k0 + sch * 8) << 1),
                    Bs + it * 4096 + wv * 1024);
        }
        __syncthreads();
        #pragma unroll
        for (int kk = 0; kk < 2; ++kk) {
            bf16x8 av[4], bv[4];
            #pragma unroll
            for (int f = 0; f < 4; ++f) {
                int ra = wm * 64 + f * 16 + l15;
                av[f] = *(const bf16x8*)(As + ra * 128 + ((((kk << 2) | lg) ^ (ra & 7)) << 4));
                int rb = wn * 64 + f * 16 + l15;
                bv[f] = *(const bf16x8*)(Bs + rb * 128 + ((((kk << 2) | lg) ^ (rb & 7)) << 4));
            }
            #pragma unroll
            for (int mf = 0; mf < 4; ++mf)
                #pragma unroll
                for (int nf = 0; nf < 4; ++nf)
                    acc[mf][nf] = __builtin_amdgcn_mfma_f32_16x16x32_bf16(
                        av[mf], bv[nf], acc[mf][nf], 0, 0, 0);
        }
        __syncthreads();
    }

    #pragma unroll
    for (int mf = 0; mf < 4; ++mf) {
        int m0 = bm + wm * 64 + mf * 16 + lg * 4;
        #pragma unroll
        for (int nf = 0; nf < 4; ++nf) {
            int n0 = bn + wn * 64 + nf * 16 + l15;
            if (mode == 0) {
                #pragma unroll
                for (int r = 0; r < 4; ++r)
                    Cf[(size_t)(m0 + r) * 2048 + n0] = acc[mf][nf][r];
            } else if (n0 < 2048) {
                #pragma unroll
                for (int r = 0; r < 4; ++r)
                    Cq[(size_t)(m0 + r) * 2048 + n0] = f2bf(acc[mf][nf][r]);
            } else if (n0 < 3072) {
                #pragma unroll
                for (int r = 0; r < 4; ++r)
                    Ck[(size_t)(m0 + r) * 1024 + (n0 - 2048)] = f2bf(acc[mf][nf][r]);
            } else {
                ushort4 u;
                u.x = f2bf(acc[mf][nf][0]); u.y = f2bf(acc[mf][nf][1]);
                u.z = f2bf(acc[mf][nf][2]); u.w = f2bf(acc[mf][nf][3]);
                *(ushort4*)&Cv[(size_t)(n0 - 3072) * 2048 + m0] = u;
            }
        }
    }
}

// ---------------------------------------------------------------------------
// In-place RoPE on bf16 P[T][H*128].
// ---------------------------------------------------------------------------
__global__ __launch_bounds__(256) void rope_bf16(
    unsigned short* __restrict__ P, const float* __restrict__ cosT,
    const float* __restrict__ sinT, int H)
{
    int idx = blockIdx.x * 256 + threadIdx.x;
    int d = idx & 63;
    int h = (idx >> 6) % H;
    int t = idx / (64 * H);
    float c = cosT[t * HDIM + d];
    float s = sinT[t * HDIM + d];
    unsigned short* row = P + (size_t)t * (H * HDIM) + h * HDIM;
    float x0 = bf2f((short)row[d]), x1 = bf2f((short)row[d + 64]);
    row[d]      = f2bf(x0 * c - x1 * s);
    row[d + 64] = f2bf(x1 * c + x0 * s);
}

// ---------------------------------------------------------------------------
// MFMA flash attention + 4 depth slots (unchanged from R2 except bf16 output).
// ---------------------------------------------------------------------------
__global__ __launch_bounds__(256) void attn_mfma(
    const unsigned short* __restrict__ Qb, const unsigned short* __restrict__ Kb,
    const unsigned short* __restrict__ Vt,
    const float* __restrict__ Dk, const float* __restrict__ Dv,
    unsigned short* __restrict__ AO)
{
    __shared__ char lds[8192 + 8192 + 4096];
    char* Ks = lds;
    char* Vs = lds + 8192;
    char* Ps = lds + 16384;

    const int hq = blockIdx.y, hk = hq >> 1;
    const int q0 = ((int)gridDim.x - 1 - (int)blockIdx.x) * 64;
    const int tid = threadIdx.x;
    const int wv = tid >> 6, lane = tid & 63;
    const int l15 = lane & 15, lg = lane >> 4;
    const size_t DSTRIDE = (size_t)NHK * T_SEQ * HDIM;

    const int trow_a = q0 + wv * 16 + l15;
    bf16x8 qf[4];
    {
        const unsigned short* qrow = Qb + (size_t)trow_a * DMODEL + hq * HDIM;
        #pragma unroll
        for (int c = 0; c < 4; ++c)
            qf[c] = *(const bf16x8*)(qrow + c * 32 + lg * 8);
    }

    f32x4 oacc[8];
    #pragma unroll
    for (int dt = 0; dt < 8; ++dt) oacc[dt] = (f32x4){0.f, 0.f, 0.f, 0.f};
    float mrun[4], lrun[4];
    #pragma unroll
    for (int r = 0; r < 4; ++r) { mrun[r] = -1e30f; lrun[r] = 0.f; }

    const int trow_c = q0 + wv * 16 + lg * 4;
    const int pswz = (l15 ^ (l15 >> 2)) & 3;

    const int jend = q0 + 64;
    for (int j0 = 0; j0 < jend; j0 += 32) {
        #pragma unroll
        for (int it = 0; it < 2; ++it) {
            int Pb = wv * 2048 + it * 1024 + lane * 16;
            int row = Pb >> 8;
            int cl  = ((Pb >> 4) & 15) ^ (row & 7);
            gload16((const char*)Kb + (size_t)(j0 + row) * (NHK * HDIM * 2) + hk * 256 + cl * 16,
                    Ks + wv * 2048 + it * 1024);
            int d  = Pb >> 6;
            int cv = ((Pb >> 4) & 3) ^ ((d ^ (d >> 2)) & 3);
            gload16((const char*)Vt + (size_t)(hk * 128 + d) * (T_SEQ * 2) + (size_t)j0 * 2 + cv * 16,
                    Vs + wv * 2048 + it * 1024);
        }
        __syncthreads();

        if (j0 <= q0 + wv * 16 + 15) {
            f32x4 sa[2];
            #pragma unroll
            for (int s = 0; s < 2; ++s) {
                sa[s] = (f32x4){0.f, 0.f, 0.f, 0.f};
                int row = s * 16 + l15;
                #pragma unroll
                for (int c = 0; c < 4; ++c) {
                    int ch = (c * 4 + lg) ^ (row & 7);
                    bf16x8 kf = *(const bf16x8*)(Ks + row * 256 + ch * 16);
                    sa[s] = __builtin_amdgcn_mfma_f32_16x16x32_bf16(qf[c], kf, sa[s], 0, 0, 0);
                }
            }
            float p[2][4];
            #pragma unroll
            for (int s = 0; s < 2; ++s)
                #pragma unroll
                for (int r = 0; r < 4; ++r) {
                    int key = j0 + s * 16 + l15;
                    float v = sa[s][r] * ATT_SCALE;
                    p[s][r] = (key <= trow_c + r) ? v : -1e30f;
                }
            float rs[4];
            #pragma unroll
            for (int r = 0; r < 4; ++r) {
                float v = fmaxf(p[0][r], p[1][r]);
                v = fmaxf(v, __shfl_xor(v, 1));
                v = fmaxf(v, __shfl_xor(v, 2));
                v = fmaxf(v, __shfl_xor(v, 4));
                v = fmaxf(v, __shfl_xor(v, 8));
                float mn = fmaxf(mrun[r], v);
                rs[r] = __expf(mrun[r] - mn);
                mrun[r] = mn;
            }
            #pragma unroll
            for (int s = 0; s < 2; ++s)
                #pragma unroll
                for (int r = 0; r < 4; ++r)
                    p[s][r] = __expf(p[s][r] - mrun[r]);
            #pragma unroll
            for (int r = 0; r < 4; ++r) {
                float sum = p[0][r] + p[1][r];
                sum += __shfl_xor(sum, 1);
                sum += __shfl_xor(sum, 2);
                sum += __shfl_xor(sum, 4);
                sum += __shfl_xor(sum, 8);
                lrun[r] = lrun[r] * rs[r] + sum;
                #pragma unroll
                for (int dt = 0; dt < 8; ++dt) oacc[dt][r] *= rs[r];
            }
            char* pw = Ps + wv * 1024;
            #pragma unroll
            for (int s = 0; s < 2; ++s)
                #pragma unroll
                for (int r = 0; r < 4; ++r) {
                    int row = lg * 4 + r;
                    int key = s * 16 + l15;
                    int ch = (key >> 3) ^ ((r ^ lg) & 3);
                    *(unsigned short*)(pw + row * 64 + ch * 16 + (key & 7) * 2) = f2bf(p[s][r]);
                }
            asm volatile("" ::: "memory");
            {
                bf16x8 pa = *(const bf16x8*)(pw + l15 * 64 + (lg ^ pswz) * 16);
                #pragma unroll
                for (int dt = 0; dt < 8; ++dt) {
                    int d = dt * 16 + l15;
                    bf16x8 vf = *(const bf16x8*)(Vs + d * 64 + (lg ^ pswz) * 16);
                    oacc[dt] = __builtin_amdgcn_mfma_f32_16x16x32_bf16(pa, vf, oacc[dt], 0, 0, 0);
                }
            }
        }
        __syncthreads();
    }

    float dl[NL];
    #pragma unroll
    for (int sl = 0; sl < NL; ++sl) {
        const float* kd = Dk + sl * DSTRIDE + ((size_t)hk * T_SEQ + trow_a) * HDIM;
        float acc = 0.f;
        #pragma unroll
        for (int c = 0; c < 4; ++c) {
            const float* kc = kd + c * 32 + lg * 8;
            #pragma unroll
            for (int j = 0; j < 8; ++j)
                acc = fmaf(bf2f(qf[c][j]), kc[j], acc);
        }
        acc += __shfl_xor(acc, 16);
        acc += __shfl_xor(acc, 32);
        dl[sl] = acc * ATT_SCALE;
    }
    #pragma unroll
    for (int r = 0; r < 4; ++r) {
        int src = trow_c + r - q0 - wv * 16;
        float d0 = __shfl(dl[0], src);
        float d1 = __shfl(dl[1], src);
        float d2 = __shfl(dl[2], src);
        float d3 = __shfl(dl[3], src);
        float vm = fmaxf(fmaxf(d0, d1), fmaxf(d2, d3));
        float mn = fmaxf(mrun[r], vm);
        float rs = __expf(mrun[r] - mn);
        float p0 = __expf(d0 - mn), p1 = __expf(d1 - mn);
        float p2 = __expf(d2 - mn), p3 = __expf(d3 - mn);
        lrun[r] = lrun[r] * rs + (p0 + p1 + p2 + p3);
        int t = trow_c + r;
        #pragma unroll
        for (int dt = 0; dt < 8; ++dt) {
            const float* vb = Dv + ((size_t)hk * T_SEQ + t) * HDIM + dt * 16 + l15;
            float o = oacc[dt][r] * rs;
            o = fmaf(p0, vb[0], o);
            o = fmaf(p1, vb[DSTRIDE], o);
            o = fmaf(p2, vb[2 * DSTRIDE], o);
            o = fmaf(p3, vb[3 * DSTRIDE], o);
            oacc[dt][r] = o;
        }
    }
    #pragma unroll
    for (int r = 0; r < 4; ++r) {
        float inv = 1.f / lrun[r];
        unsigned short* orow = AO + (size_t)(trow_c + r) * DMODEL + hq * HDIM;
        #pragma unroll
        for (int dt = 0; dt < 8; ++dt)
            orow[dt * 16 + l15] = f2bf(oacc[dt][r] * inv);
    }
}

// ---------------------------------------------------------------------------
extern "C" void kernel_launch(void* const* d_in, const int* in_sizes, int n_in,
                              void* d_out, int out_size, void* d_ws, size_t ws_size,
                              hipStream_t stream) {
    const float* x    = (const float*)d_in[0];
    const float* dk   = (const float*)d_in[1];
    const float* dv   = (const float*)d_in[2];
    const float* cosT = (const float*)d_in[3];
    const float* sinT = (const float*)d_in[4];
    const float* Wq   = (const float*)d_in[5];
    const float* Wk   = (const float*)d_in[6];
    const float* Wv   = (const float*)d_in[7];
    const float* Wo   = (const float*)d_in[8];
    float* out = (float*)d_out;

    // ws (ushort elems): xb/AOb 4M | Qb 4M | Kb 2M | Vt 2M | WTproj 8M | WoT 4M
    // = 24M ushorts = 48 MB. AOb aliases xb (xb dead after proj GEMM).
    unsigned short* xb  = (unsigned short*)d_ws;
    unsigned short* Qb  = xb + (size_t)4 * 1024 * 1024;
    unsigned short* Kb  = Qb + (size_t)4 * 1024 * 1024;
    unsigned short* Vt  = Kb + (size_t)2 * 1024 * 1024;
    unsigned short* WTp = Vt + (size_t)2 * 1024 * 1024;
    unsigned short* WoT = WTp + (size_t)8 * 1024 * 1024;
    unsigned short* AOb = xb;

    // casts
    cast_f32_bf16<<<dim3(2048), 256, 0, stream>>>(x, xb);
    tcast<<<dim3(32, 32), 256, 0, stream>>>(Wq, WTp, 2048, 2048, 0);
    tcast<<<dim3(32, 16), 256, 0, stream>>>(Wk, WTp, 1024, 2048, 2048);
    tcast<<<dim3(32, 16), 256, 0, stream>>>(Wv, WTp, 1024, 2048, 3072);
    tcast<<<dim3(32, 32), 256, 0, stream>>>(Wo, WoT, 2048, 2048, 0);
    // fused Q/K/V projection (N=4096)
    gemm_bt<<<dim3(32, 16), 256, 0, stream>>>(xb, WTp, nullptr, Qb, Kb, Vt, 1, DMODEL);
    // RoPE
    rope_bf16<<<dim3(T_SEQ * NHQ * 64 / 256), 256, 0, stream>>>(Qb, cosT, sinT, NHQ);
    rope_bf16<<<dim3(T_SEQ * NHK * 64 / 256), 256, 0, stream>>>(Kb, cosT, sinT, NHK);
    // attention
    attn_mfma<<<dim3(T_SEQ / 64, NHQ), 256, 0, stream>>>(Qb, Kb, Vt, dk, dv, AOb);
    // output projection (f32 out)
    gemm_bt<<<dim3(16, 16), 256, 0, stream>>>(AOb, WoT, out, nullptr, nullptr, nullptr, 0, DMODEL);
}

// Round 4
// 226.489 us; speedup vs baseline: 9.4835x; 1.1296x over previous
//
#include <hip/hip_runtime.h>
#include <hip/hip_bf16.h>
#include <math.h>

#define T_SEQ 2048
#define DMODEL 2048
#define NHQ 16
#define NHK 8
#define HDIM 128
#define NL 4
#define ATT_SCALE 0.08838834764831845f  // 1/sqrt(128)

typedef __attribute__((ext_vector_type(8))) short bf16x8;
typedef __attribute__((ext_vector_type(4))) float f32x4;

__device__ __forceinline__ float bf2f(short u) {
    union { float f; unsigned int i; } x;
    x.i = ((unsigned int)(unsigned short)u) << 16;
    return x.f;
}
__device__ __forceinline__ unsigned short f2bf(float f) {
    __hip_bfloat16 h = __float2bfloat16(f);
    return *reinterpret_cast<unsigned short*>(&h);
}
__device__ __forceinline__ void gload16(const void* g, void* l) {
    __builtin_amdgcn_global_load_lds(
        (const __attribute__((address_space(1))) void*)g,
        (__attribute__((address_space(3))) void*)l, 16, 0, 0);
}

// ---------------------------------------------------------------------------
// Cast fp32 -> bf16, 8 elems/thread.
// ---------------------------------------------------------------------------
__global__ __launch_bounds__(256) void cast_f32_bf16(
    const float* __restrict__ s, unsigned short* __restrict__ d)
{
    int i = blockIdx.x * 256 + threadIdx.x;
    float4 a = ((const float4*)s)[2 * i];
    float4 b = ((const float4*)s)[2 * i + 1];
    bf16x8 v;
    v[0] = (short)f2bf(a.x); v[1] = (short)f2bf(a.y);
    v[2] = (short)f2bf(a.z); v[3] = (short)f2bf(a.w);
    v[4] = (short)f2bf(b.x); v[5] = (short)f2bf(b.y);
    v[6] = (short)f2bf(b.z); v[7] = (short)f2bf(b.w);
    ((bf16x8*)d)[i] = v;
}

// ---------------------------------------------------------------------------
// Transpose-cast: src fp32 [Ksrc][Nsrc] -> dst bf16 [Nsrc][Ksrc] @ dstOff.
// ---------------------------------------------------------------------------
__global__ __launch_bounds__(256) void tcast(
    const float* __restrict__ src, unsigned short* __restrict__ dst,
    int Nsrc, int Ksrc, int dstOff)
{
    __shared__ float ls[64][65];
    const int k0 = blockIdx.x * 64, n0 = blockIdx.y * 64;
    const int tid = threadIdx.x;
    #pragma unroll
    for (int it = 0; it < 4; ++it) {
        int fi = tid + it * 256;
        int r = fi >> 4;
        int c = (fi & 15) * 4;
        float4 v = *(const float4*)&src[(size_t)(k0 + r) * Nsrc + n0 + c];
        ls[r][c] = v.x; ls[r][c + 1] = v.y; ls[r][c + 2] = v.z; ls[r][c + 3] = v.w;
    }
    __syncthreads();
    int n = tid & 63, kc = tid >> 6;
    bf16x8 v0, v1;
    #pragma unroll
    for (int j = 0; j < 8; ++j) v0[j] = (short)f2bf(ls[kc * 16 + j][n]);
    #pragma unroll
    for (int j = 0; j < 8; ++j) v1[j] = (short)f2bf(ls[kc * 16 + 8 + j][n]);
    size_t drow = (size_t)(dstOff + n0 + n) * Ksrc + k0 + kc * 16;
    *(bf16x8*)&dst[drow] = v0;
    *(bf16x8*)&dst[drow + 8] = v1;
}

// ---------------------------------------------------------------------------
// bf16 MFMA GEMM (m97 structure), C = A * Bt^T. Unchanged from R3.
// ---------------------------------------------------------------------------
__global__ __launch_bounds__(256) void gemm_bt(
    const unsigned short* __restrict__ A, const unsigned short* __restrict__ Bt,
    float* __restrict__ Cf, unsigned short* __restrict__ Cq,
    unsigned short* __restrict__ Ck, unsigned short* __restrict__ Cv,
    int mode, int K)
{
    __shared__ char As[16384];
    __shared__ char Bs[16384];
    const int tid = threadIdx.x;
    const int wv = tid >> 6, lane = tid & 63;
    const int l15 = lane & 15, lg = lane >> 4;
    const int wm = wv >> 1, wn = wv & 1;
    const int bm = blockIdx.y * 128, bn = blockIdx.x * 128;

    f32x4 acc[4][4];
    #pragma unroll
    for (int i = 0; i < 4; ++i)
        #pragma unroll
        for (int j = 0; j < 4; ++j)
            acc[i][j] = (f32x4){0.f, 0.f, 0.f, 0.f};

    for (int k0 = 0; k0 < K; k0 += 64) {
        #pragma unroll
        for (int it = 0; it < 4; ++it) {
            int o = it * 4096 + tid * 16;
            int row = o >> 7;
            int sch = ((o >> 4) & 7) ^ (row & 7);
            gload16((const char*)A + ((((size_t)(bm + row) * K) + k0 + sch * 8) << 1),
                    As + it * 4096 + wv * 1024);
            gload16((const char*)Bt + ((((size_t)(bn + row) * K) + k0 + sch * 8) << 1),
                    Bs + it * 4096 + wv * 1024);
        }
        __syncthreads();
        #pragma unroll
        for (int kk = 0; kk < 2; ++kk) {
            bf16x8 av[4], bv[4];
            #pragma unroll
            for (int f = 0; f < 4; ++f) {
                int ra = wm * 64 + f * 16 + l15;
                av[f] = *(const bf16x8*)(As + ra * 128 + ((((kk << 2) | lg) ^ (ra & 7)) << 4));
                int rb = wn * 64 + f * 16 + l15;
                bv[f] = *(const bf16x8*)(Bs + rb * 128 + ((((kk << 2) | lg) ^ (rb & 7)) << 4));
            }
            #pragma unroll
            for (int mf = 0; mf < 4; ++mf)
                #pragma unroll
                for (int nf = 0; nf < 4; ++nf)
                    acc[mf][nf] = __builtin_amdgcn_mfma_f32_16x16x32_bf16(
                        av[mf], bv[nf], acc[mf][nf], 0, 0, 0);
        }
        __syncthreads();
    }

    #pragma unroll
    for (int mf = 0; mf < 4; ++mf) {
        int m0 = bm + wm * 64 + mf * 16 + lg * 4;
        #pragma unroll
        for (int nf = 0; nf < 4; ++nf) {
            int n0 = bn + wn * 64 + nf * 16 + l15;
            if (mode == 0) {
                #pragma unroll
                for (int r = 0; r < 4; ++r)
                    Cf[(size_t)(m0 + r) * 2048 + n0] = acc[mf][nf][r];
            } else if (n0 < 2048) {
                #pragma unroll
                for (int r = 0; r < 4; ++r)
                    Cq[(size_t)(m0 + r) * 2048 + n0] = f2bf(acc[mf][nf][r]);
            } else if (n0 < 3072) {
                #pragma unroll
                for (int r = 0; r < 4; ++r)
                    Ck[(size_t)(m0 + r) * 1024 + (n0 - 2048)] = f2bf(acc[mf][nf][r]);
            } else {
                ushort4 u;
                u.x = f2bf(acc[mf][nf][0]); u.y = f2bf(acc[mf][nf][1]);
                u.z = f2bf(acc[mf][nf][2]); u.w = f2bf(acc[mf][nf][3]);
                *(ushort4*)&Cv[(size_t)(n0 - 3072) * 2048 + m0] = u;
            }
        }
    }
}

// ---------------------------------------------------------------------------
// In-place RoPE on bf16 P[T][H*128].
// ---------------------------------------------------------------------------
__global__ __launch_bounds__(256) void rope_bf16(
    unsigned short* __restrict__ P, const float* __restrict__ cosT,
    const float* __restrict__ sinT, int H)
{
    int idx = blockIdx.x * 256 + threadIdx.x;
    int d = idx & 63;
    int h = (idx >> 6) % H;
    int t = idx / (64 * H);
    float c = cosT[t * HDIM + d];
    float s = sinT[t * HDIM + d];
    unsigned short* row = P + (size_t)t * (H * HDIM) + h * HDIM;
    float x0 = bf2f((short)row[d]), x1 = bf2f((short)row[d + 64]);
    row[d]      = f2bf(x0 * c - x1 * s);
    row[d + 64] = f2bf(x1 * c + x0 * s);
}

// ---------------------------------------------------------------------------
// MFMA flash attention, swapped-QK layout. Block = 4 waves = 64 q-rows, 1 head.
// KVBLK=64. S = mfma(K,Q): col(l15)=q, row(lg*4+reg)=key -> softmax state is
// per-lane scalar (m,l at q=l15), reduces are 2x shfl_xor(16,32).
// P staged per-wave in LDS [16 q][128B keys], chunk^=(q&7) -> 2-way writes.
// PV = mfma(P,V): col=d, row=q=lg*4+reg. Balanced block order: all heads'
// long (high-q0) blocks first.
// ---------------------------------------------------------------------------
__global__ __launch_bounds__(256) void attn_mfma(
    const unsigned short* __restrict__ Qb, const unsigned short* __restrict__ Kb,
    const unsigned short* __restrict__ Vt,
    const float* __restrict__ Dk, const float* __restrict__ Dv,
    unsigned short* __restrict__ AO)
{
    __shared__ char Ks[16384];   // [64 keys][128 d] bf16, 16B chunks ^= row&7
    __shared__ char Vs[16384];   // [128 d][64 keys] bf16, 16B chunks ^= row&7
    __shared__ char Ps[8192];    // 4 waves x [16 q][64 keys] bf16, ch ^= q&7

    const int bid = blockIdx.x;
    const int hq = bid & 15, hk = hq >> 1;
    const int q0 = (31 - (bid >> 4)) * 64;
    const int tid = threadIdx.x;
    const int wv = tid >> 6, lane = tid & 63;
    const int l15 = lane & 15, lg = lane >> 4;
    const size_t DSTRIDE = (size_t)NHK * T_SEQ * HDIM;

    const int tq = q0 + wv * 16 + l15;     // softmax-domain q row (per lane)
    const int qmax = q0 + wv * 16 + 15;    // wave's max q

    // Q B-frag: lane l15 = q col, k = d = c*32 + lg*8 + j (contiguous load)
    bf16x8 qf[4];
    {
        const unsigned short* qrow = Qb + (size_t)tq * DMODEL + hq * HDIM;
        #pragma unroll
        for (int c = 0; c < 4; ++c)
            qf[c] = *(const bf16x8*)(qrow + c * 32 + lg * 8);
    }

    f32x4 oacc[8];
    #pragma unroll
    for (int dt = 0; dt < 8; ++dt) oacc[dt] = (f32x4){0.f, 0.f, 0.f, 0.f};
    float m = -1e30f, l = 0.f;

    for (int j0 = 0; j0 <= q0; j0 += 64) {
        // ---- stage K[64][128] and Vt[128][64], pre-swizzled source ----
        #pragma unroll
        for (int it = 0; it < 4; ++it) {
            int o = it * 4096 + tid * 16;
            int rk = o >> 8, ck = (o >> 4) & 15;
            gload16((const char*)Kb +
                    (((size_t)(j0 + rk) * 1024 + hk * 128 + ((ck ^ (rk & 7)) << 3)) << 1),
                    Ks + it * 4096 + wv * 1024);
            int rv = o >> 7, cv = (o >> 4) & 7;
            gload16((const char*)Vt +
                    (((size_t)(hk * 128 + rv) * 2048 + j0 + ((cv ^ (rv & 7)) << 3)) << 1),
                    Vs + it * 4096 + wv * 1024);
        }
        __syncthreads();

        // ---- S^T = K Q : 4 key-subtiles x 4 d-chunks ----
        float p[4][4];
        #pragma unroll
        for (int s = 0; s < 4; ++s) {
            if (j0 + s * 16 <= qmax) {
                f32x4 sa = (f32x4){0.f, 0.f, 0.f, 0.f};
                int row = s * 16 + l15;                 // key row (A-frag)
                #pragma unroll
                for (int c = 0; c < 4; ++c) {
                    int ch = (c * 4 + lg) ^ (row & 7);
                    bf16x8 kf = *(const bf16x8*)(Ks + row * 256 + ch * 16);
                    sa = __builtin_amdgcn_mfma_f32_16x16x32_bf16(kf, qf[c], sa, 0, 0, 0);
                }
                #pragma unroll
                for (int r = 0; r < 4; ++r) {
                    int key = j0 + s * 16 + lg * 4 + r;
                    p[s][r] = (key <= tq) ? sa[r] * ATT_SCALE : -1e30f;
                }
            } else {
                #pragma unroll
                for (int r = 0; r < 4; ++r) p[s][r] = -1e30f;
            }
        }
        // ---- online softmax (per-lane q; reduce over lg via 2 shfls) ----
        float vmax = p[0][0];
        #pragma unroll
        for (int s = 0; s < 4; ++s)
            #pragma unroll
            for (int r = 0; r < 4; ++r) vmax = fmaxf(vmax, p[s][r]);
        vmax = fmaxf(vmax, __shfl_xor(vmax, 16));
        vmax = fmaxf(vmax, __shfl_xor(vmax, 32));
        float mn = fmaxf(m, vmax);
        float rs = __expf(m - mn);
        m = mn;
        float sum = 0.f;
        #pragma unroll
        for (int s = 0; s < 4; ++s)
            #pragma unroll
            for (int r = 0; r < 4; ++r) {
                float pe = __expf(p[s][r] - m);
                p[s][r] = pe;
                sum += pe;
            }
        sum += __shfl_xor(sum, 16);
        sum += __shfl_xor(sum, 32);
        l = l * rs + sum;
        // rescale O (rows q = lg*4+r): fetch rs of that q
        float rs_o[4];
        #pragma unroll
        for (int r = 0; r < 4; ++r) rs_o[r] = __shfl(rs, lg * 4 + r);
        #pragma unroll
        for (int dt = 0; dt < 8; ++dt)
            #pragma unroll
            for (int r = 0; r < 4; ++r) oacc[dt][r] *= rs_o[r];

        // ---- P -> per-wave LDS (row = q = l15, swizzled chunks) ----
        char* pw = Ps + wv * 2048;
        #pragma unroll
        for (int s = 0; s < 4; ++s)
            #pragma unroll
            for (int r = 0; r < 4; ++r) {
                int key = s * 16 + lg * 4 + r;
                int ch = (key >> 3) ^ (l15 & 7);
                *(unsigned short*)(pw + l15 * 128 + ch * 16 + (key & 7) * 2) = f2bf(p[s][r]);
            }
        asm volatile("" ::: "memory");
        // ---- PV: O += P V  (A = P rows q=l15, B = V cols d=l15) ----
        #pragma unroll
        for (int c = 0; c < 2; ++c) {
            if (j0 + c * 32 <= qmax) {
                bf16x8 pa = *(const bf16x8*)(pw + l15 * 128 + (((c * 4 + lg) ^ (l15 & 7)) << 4));
                #pragma unroll
                for (int dt = 0; dt < 8; ++dt) {
                    int rv = dt * 16 + l15;
                    bf16x8 vf = *(const bf16x8*)(Vs + rv * 128 + (((c * 4 + lg) ^ (rv & 7)) << 4));
                    oacc[dt] = __builtin_amdgcn_mfma_f32_16x16x32_bf16(pa, vf, oacc[dt], 0, 0, 0);
                }
            }
        }
        __syncthreads();
    }

    // ---- depth slots (per-lane q = tq) ----
    float dl[NL];
    #pragma unroll
    for (int sl = 0; sl < NL; ++sl) {
        const float* kd = Dk + sl * DSTRIDE + ((size_t)hk * T_SEQ + tq) * HDIM;
        float a = 0.f;
        #pragma unroll
        for (int c = 0; c < 4; ++c) {
            const float* kc = kd + c * 32 + lg * 8;
            #pragma unroll
            for (int j = 0; j < 8; ++j)
                a = fmaf(bf2f(qf[c][j]), kc[j], a);
        }
        a += __shfl_xor(a, 16);
        a += __shfl_xor(a, 32);
        dl[sl] = a * ATT_SCALE;
    }
    float vm = fmaxf(fmaxf(dl[0], dl[1]), fmaxf(dl[2], dl[3]));
    float mn = fmaxf(m, vm);
    float rsd = __expf(m - mn);
    float pd[NL];
    #pragma unroll
    for (int sl = 0; sl < NL; ++sl) pd[sl] = __expf(dl[sl] - mn);
    l = l * rsd + (pd[0] + pd[1] + pd[2] + pd[3]);
    float linv = 1.f / l;
    // redistribute to O-domain (q = lg*4+r)
    float rs_o[4], li_o[4], pdo[NL][4];
    #pragma unroll
    for (int r = 0; r < 4; ++r) {
        rs_o[r] = __shfl(rsd, lg * 4 + r);
        li_o[r] = __shfl(linv, lg * 4 + r);
        #pragma unroll
        for (int sl = 0; sl < NL; ++sl) pdo[sl][r] = __shfl(pd[sl], lg * 4 + r);
    }
    #pragma unroll
    for (int r = 0; r < 4; ++r) {
        int t = q0 + wv * 16 + lg * 4 + r;
        #pragma unroll
        for (int dt = 0; dt < 8; ++dt) {
            const float* vb = Dv + ((size_t)hk * T_SEQ + t) * HDIM + dt * 16 + l15;
            float o = oacc[dt][r] * rs_o[r];
            o = fmaf(pdo[0][r], vb[0], o);
            o = fmaf(pdo[1][r], vb[DSTRIDE], o);
            o = fmaf(pdo[2][r], vb[2 * DSTRIDE], o);
            o = fmaf(pdo[3][r], vb[3 * DSTRIDE], o);
            oacc[dt][r] = o * li_o[r];
        }
    }
    // ---- store (col = l15 = d -> coalesced 32B segments) ----
    #pragma unroll
    for (int r = 0; r < 4; ++r) {
        unsigned short* orow = AO + (size_t)(q0 + wv * 16 + lg * 4 + r) * DMODEL + hq * HDIM;
        #pragma unroll
        for (int dt = 0; dt < 8; ++dt)
            orow[dt * 16 + l15] = f2bf(oacc[dt][r]);
    }
}

// ---------------------------------------------------------------------------
extern "C" void kernel_launch(void* const* d_in, const int* in_sizes, int n_in,
                              void* d_out, int out_size, void* d_ws, size_t ws_size,
                              hipStream_t stream) {
    const float* x    = (const float*)d_in[0];
    const float* dk   = (const float*)d_in[1];
    const float* dv   = (const float*)d_in[2];
    const float* cosT = (const float*)d_in[3];
    const float* sinT = (const float*)d_in[4];
    const float* Wq   = (const float*)d_in[5];
    const float* Wk   = (const float*)d_in[6];
    const float* Wv   = (const float*)d_in[7];
    const float* Wo   = (const float*)d_in[8];
    float* out = (float*)d_out;

    unsigned short* xb  = (unsigned short*)d_ws;
    unsigned short* Qb  = xb + (size_t)4 * 1024 * 1024;
    unsigned short* Kb  = Qb + (size_t)4 * 1024 * 1024;
    unsigned short* Vt  = Kb + (size_t)2 * 1024 * 1024;
    unsigned short* WTp = Vt + (size_t)2 * 1024 * 1024;
    unsigned short* WoT = WTp + (size_t)8 * 1024 * 1024;
    unsigned short* AOb = xb;   // alias: xb dead after proj GEMM

    cast_f32_bf16<<<dim3(2048), 256, 0, stream>>>(x, xb);
    tcast<<<dim3(32, 32), 256, 0, stream>>>(Wq, WTp, 2048, 2048, 0);
    tcast<<<dim3(32, 16), 256, 0, stream>>>(Wk, WTp, 1024, 2048, 2048);
    tcast<<<dim3(32, 16), 256, 0, stream>>>(Wv, WTp, 1024, 2048, 3072);
    tcast<<<dim3(32, 32), 256, 0, stream>>>(Wo, WoT, 2048, 2048, 0);
    gemm_bt<<<dim3(32, 16), 256, 0, stream>>>(xb, WTp, nullptr, Qb, Kb, Vt, 1, DMODEL);
    rope_bf16<<<dim3(T_SEQ * NHQ * 64 / 256), 256, 0, stream>>>(Qb, cosT, sinT, NHQ);
    rope_bf16<<<dim3(T_SEQ * NHK * 64 / 256), 256, 0, stream>>>(Kb, cosT, sinT, NHK);
    attn_mfma<<<dim3(512), 256, 0, stream>>>(Qb, Kb, Vt, dk, dv, AOb);
    gemm_bt<<<dim3(16, 16), 256, 0, stream>>>(AOb, WoT, out, nullptr, nullptr, nullptr, 0, DMODEL);
}

// Round 5
// 202.143 us; speedup vs baseline: 10.6257x; 1.1204x over previous
//
#include <hip/hip_runtime.h>
#include <hip/hip_bf16.h>
#include <math.h>

#define T_SEQ 2048
#define DMODEL 2048
#define NHQ 16
#define NHK 8
#define HDIM 128
#define NL 4
#define ATT_SCALE 0.08838834764831845f  // 1/sqrt(128)

typedef __attribute__((ext_vector_type(8))) short bf16x8;
typedef __attribute__((ext_vector_type(4))) float f32x4;

__device__ __forceinline__ float bf2f(short u) {
    union { float f; unsigned int i; } x;
    x.i = ((unsigned int)(unsigned short)u) << 16;
    return x.f;
}
__device__ __forceinline__ unsigned short f2bf(float f) {
    __hip_bfloat16 h = __float2bfloat16(f);
    return *reinterpret_cast<unsigned short*>(&h);
}
__device__ __forceinline__ void gload16(const void* g, void* l) {
    __builtin_amdgcn_global_load_lds(
        (const __attribute__((address_space(1))) void*)g,
        (__attribute__((address_space(3))) void*)l, 16, 0, 0);
}

// ---------------------------------------------------------------------------
// Cast fp32 -> bf16, 8 elems/thread.
// ---------------------------------------------------------------------------
__global__ __launch_bounds__(256) void cast_f32_bf16(
    const float* __restrict__ s, unsigned short* __restrict__ d)
{
    int i = blockIdx.x * 256 + threadIdx.x;
    float4 a = ((const float4*)s)[2 * i];
    float4 b = ((const float4*)s)[2 * i + 1];
    bf16x8 v;
    v[0] = (short)f2bf(a.x); v[1] = (short)f2bf(a.y);
    v[2] = (short)f2bf(a.z); v[3] = (short)f2bf(a.w);
    v[4] = (short)f2bf(b.x); v[5] = (short)f2bf(b.y);
    v[6] = (short)f2bf(b.z); v[7] = (short)f2bf(b.w);
    ((bf16x8*)d)[i] = v;
}

// ---------------------------------------------------------------------------
// Transpose-cast: src fp32 [Ksrc][Nsrc] -> dst bf16 [Nsrc][Ksrc] @ dstOff.
// ---------------------------------------------------------------------------
__global__ __launch_bounds__(256) void tcast(
    const float* __restrict__ src, unsigned short* __restrict__ dst,
    int Nsrc, int Ksrc, int dstOff)
{
    __shared__ float ls[64][65];
    const int k0 = blockIdx.x * 64, n0 = blockIdx.y * 64;
    const int tid = threadIdx.x;
    #pragma unroll
    for (int it = 0; it < 4; ++it) {
        int fi = tid + it * 256;
        int r = fi >> 4;
        int c = (fi & 15) * 4;
        float4 v = *(const float4*)&src[(size_t)(k0 + r) * Nsrc + n0 + c];
        ls[r][c] = v.x; ls[r][c + 1] = v.y; ls[r][c + 2] = v.z; ls[r][c + 3] = v.w;
    }
    __syncthreads();
    int n = tid & 63, kc = tid >> 6;
    bf16x8 v0, v1;
    #pragma unroll
    for (int j = 0; j < 8; ++j) v0[j] = (short)f2bf(ls[kc * 16 + j][n]);
    #pragma unroll
    for (int j = 0; j < 8; ++j) v1[j] = (short)f2bf(ls[kc * 16 + 8 + j][n]);
    size_t drow = (size_t)(dstOff + n0 + n) * Ksrc + k0 + kc * 16;
    *(bf16x8*)&dst[drow] = v0;
    *(bf16x8*)&dst[drow + 8] = v1;
}

// ---------------------------------------------------------------------------
// bf16 MFMA GEMM (m97 structure), C = A * Bt^T. Unchanged from R4.
// ---------------------------------------------------------------------------
__global__ __launch_bounds__(256) void gemm_bt(
    const unsigned short* __restrict__ A, const unsigned short* __restrict__ Bt,
    float* __restrict__ Cf, unsigned short* __restrict__ Cq,
    unsigned short* __restrict__ Ck, unsigned short* __restrict__ Cv,
    int mode, int K)
{
    __shared__ char As[16384];
    __shared__ char Bs[16384];
    const int tid = threadIdx.x;
    const int wv = tid >> 6, lane = tid & 63;
    const int l15 = lane & 15, lg = lane >> 4;
    const int wm = wv >> 1, wn = wv & 1;
    const int bm = blockIdx.y * 128, bn = blockIdx.x * 128;

    f32x4 acc[4][4];
    #pragma unroll
    for (int i = 0; i < 4; ++i)
        #pragma unroll
        for (int j = 0; j < 4; ++j)
            acc[i][j] = (f32x4){0.f, 0.f, 0.f, 0.f};

    for (int k0 = 0; k0 < K; k0 += 64) {
        #pragma unroll
        for (int it = 0; it < 4; ++it) {
            int o = it * 4096 + tid * 16;
            int row = o >> 7;
            int sch = ((o >> 4) & 7) ^ (row & 7);
            gload16((const char*)A + ((((size_t)(bm + row) * K) + k0 + sch * 8) << 1),
                    As + it * 4096 + wv * 1024);
            gload16((const char*)Bt + ((((size_t)(bn + row) * K) + k0 + sch * 8) << 1),
                    Bs + it * 4096 + wv * 1024);
        }
        __syncthreads();
        #pragma unroll
        for (int kk = 0; kk < 2; ++kk) {
            bf16x8 av[4], bv[4];
            #pragma unroll
            for (int f = 0; f < 4; ++f) {
                int ra = wm * 64 + f * 16 + l15;
                av[f] = *(const bf16x8*)(As + ra * 128 + ((((kk << 2) | lg) ^ (ra & 7)) << 4));
                int rb = wn * 64 + f * 16 + l15;
                bv[f] = *(const bf16x8*)(Bs + rb * 128 + ((((kk << 2) | lg) ^ (rb & 7)) << 4));
            }
            #pragma unroll
            for (int mf = 0; mf < 4; ++mf)
                #pragma unroll
                for (int nf = 0; nf < 4; ++nf)
                    acc[mf][nf] = __builtin_amdgcn_mfma_f32_16x16x32_bf16(
                        av[mf], bv[nf], acc[mf][nf], 0, 0, 0);
        }
        __syncthreads();
    }

    #pragma unroll
    for (int mf = 0; mf < 4; ++mf) {
        int m0 = bm + wm * 64 + mf * 16 + lg * 4;
        #pragma unroll
        for (int nf = 0; nf < 4; ++nf) {
            int n0 = bn + wn * 64 + nf * 16 + l15;
            if (mode == 0) {
                #pragma unroll
                for (int r = 0; r < 4; ++r)
                    Cf[(size_t)(m0 + r) * 2048 + n0] = acc[mf][nf][r];
            } else if (n0 < 2048) {
                #pragma unroll
                for (int r = 0; r < 4; ++r)
                    Cq[(size_t)(m0 + r) * 2048 + n0] = f2bf(acc[mf][nf][r]);
            } else if (n0 < 3072) {
                #pragma unroll
                for (int r = 0; r < 4; ++r)
                    Ck[(size_t)(m0 + r) * 1024 + (n0 - 2048)] = f2bf(acc[mf][nf][r]);
            } else {
                ushort4 u;
                u.x = f2bf(acc[mf][nf][0]); u.y = f2bf(acc[mf][nf][1]);
                u.z = f2bf(acc[mf][nf][2]); u.w = f2bf(acc[mf][nf][3]);
                *(ushort4*)&Cv[(size_t)(n0 - 3072) * 2048 + m0] = u;
            }
        }
    }
}

// ---------------------------------------------------------------------------
// In-place RoPE on bf16 P[T][H*128].
// ---------------------------------------------------------------------------
__global__ __launch_bounds__(256) void rope_bf16(
    unsigned short* __restrict__ P, const float* __restrict__ cosT,
    const float* __restrict__ sinT, int H)
{
    int idx = blockIdx.x * 256 + threadIdx.x;
    int d = idx & 63;
    int h = (idx >> 6) % H;
    int t = idx / (64 * H);
    float c = cosT[t * HDIM + d];
    float s = sinT[t * HDIM + d];
    unsigned short* row = P + (size_t)t * (H * HDIM) + h * HDIM;
    float x0 = bf2f((short)row[d]), x1 = bf2f((short)row[d + 64]);
    row[d]      = f2bf(x0 * c - x1 * s);
    row[d + 64] = f2bf(x1 * c + x0 * s);
}

// ---------------------------------------------------------------------------
// MFMA flash attention, swapped-QK layout (R4 compute) + R5 changes:
//  * XCD-pinned blocks: bid&7 = hk -> one KV-head's 64 blocks share one XCD's
//    L2 (K/V ~1MB bf16 + depth rows stay resident; staging hits L2 not HBM).
//  * Double-buffered K/V tiles, prefetch issued BEFORE compute, ONE
//    __syncthreads per tile (T3 2-phase minimum; drain after full compute).
//  * Long blocks (high q0) dispatched first within each XCD.
// ---------------------------------------------------------------------------
__global__ __launch_bounds__(256) void attn_mfma(
    const unsigned short* __restrict__ Qb, const unsigned short* __restrict__ Kb,
    const unsigned short* __restrict__ Vt,
    const float* __restrict__ Dk, const float* __restrict__ Dv,
    unsigned short* __restrict__ AO)
{
    __shared__ char Ks[2][16384];   // [64 keys][128 d] bf16, chunks ^= row&7
    __shared__ char Vs[2][16384];   // [128 d][64 keys] bf16, chunks ^= row&7
    __shared__ char Ps[8192];       // 4 waves x [16 q][64 keys] bf16, ch ^= q&7

    const int bid = blockIdx.x;
    const int hk = bid & 7;                       // == XCD (round-robin dispatch)
    const int e = bid >> 3;
    const int hq = hk * 2 + (e & 1);
    const int q0 = (31 - (e >> 1)) * 64;          // long blocks first
    const int tid = threadIdx.x;
    const int wv = tid >> 6, lane = tid & 63;
    const int l15 = lane & 15, lg = lane >> 4;
    const size_t DSTRIDE = (size_t)NHK * T_SEQ * HDIM;

    const int tq = q0 + wv * 16 + l15;     // softmax-domain q row (per lane)
    const int qmax = q0 + wv * 16 + 15;    // wave's max q

    // Q B-frag: lane l15 = q col, k = d = c*32 + lg*8 + j
    bf16x8 qf[4];
    {
        const unsigned short* qrow = Qb + (size_t)tq * DMODEL + hq * HDIM;
        #pragma unroll
        for (int c = 0; c < 4; ++c)
            qf[c] = *(const bf16x8*)(qrow + c * 32 + lg * 8);
    }

    f32x4 oacc[8];
    #pragma unroll
    for (int dt = 0; dt < 8; ++dt) oacc[dt] = (f32x4){0.f, 0.f, 0.f, 0.f};
    float m = -1e30f, l = 0.f;

    // ---- staging helper: K[64][128] + Vt[128][64], pre-swizzled source ----
    #define STAGE(J0, BUF)                                                        \
        {                                                                         \
            _Pragma("unroll")                                                     \
            for (int it = 0; it < 4; ++it) {                                      \
                int o = it * 4096 + tid * 16;                                     \
                int rk = o >> 8, ck = (o >> 4) & 15;                              \
                gload16((const char*)Kb +                                         \
                        (((size_t)((J0) + rk) * 1024 + hk * 128 +                 \
                          ((ck ^ (rk & 7)) << 3)) << 1),                          \
                        Ks[BUF] + it * 4096 + wv * 1024);                         \
                int rv = o >> 7, cv = (o >> 4) & 7;                               \
                gload16((const char*)Vt +                                         \
                        (((size_t)(hk * 128 + rv) * 2048 + (J0) +                 \
                          ((cv ^ (rv & 7)) << 3)) << 1),                          \
                        Vs[BUF] + it * 4096 + wv * 1024);                         \
            }                                                                     \
        }

    STAGE(0, 0);
    __syncthreads();
    int buf = 0;

    for (int j0 = 0; j0 <= q0; j0 += 64) {
        if (j0 + 64 <= q0) STAGE(j0 + 64, buf ^ 1);   // prefetch next tile

        const char* ksb = Ks[buf];
        const char* vsb = Vs[buf];
        // ---- S^T = K Q : 4 key-subtiles x 4 d-chunks ----
        float p[4][4];
        #pragma unroll
        for (int s = 0; s < 4; ++s) {
            if (j0 + s * 16 <= qmax) {
                f32x4 sa = (f32x4){0.f, 0.f, 0.f, 0.f};
                int row = s * 16 + l15;                 // key row (A-frag)
                #pragma unroll
                for (int c = 0; c < 4; ++c) {
                    int ch = (c * 4 + lg) ^ (row & 7);
                    bf16x8 kf = *(const bf16x8*)(ksb + row * 256 + ch * 16);
                    sa = __builtin_amdgcn_mfma_f32_16x16x32_bf16(kf, qf[c], sa, 0, 0, 0);
                }
                #pragma unroll
                for (int r = 0; r < 4; ++r) {
                    int key = j0 + s * 16 + lg * 4 + r;
                    p[s][r] = (key <= tq) ? sa[r] * ATT_SCALE : -1e30f;
                }
            } else {
                #pragma unroll
                for (int r = 0; r < 4; ++r) p[s][r] = -1e30f;
            }
        }
        // ---- online softmax (per-lane q; reduce over lg via 2 shfls) ----
        float vmax = p[0][0];
        #pragma unroll
        for (int s = 0; s < 4; ++s)
            #pragma unroll
            for (int r = 0; r < 4; ++r) vmax = fmaxf(vmax, p[s][r]);
        vmax = fmaxf(vmax, __shfl_xor(vmax, 16));
        vmax = fmaxf(vmax, __shfl_xor(vmax, 32));
        float mn = fmaxf(m, vmax);
        float rs = __expf(m - mn);
        m = mn;
        float sum = 0.f;
        #pragma unroll
        for (int s = 0; s < 4; ++s)
            #pragma unroll
            for (int r = 0; r < 4; ++r) {
                float pe = __expf(p[s][r] - m);
                p[s][r] = pe;
                sum += pe;
            }
        sum += __shfl_xor(sum, 16);
        sum += __shfl_xor(sum, 32);
        l = l * rs + sum;
        float rs_o[4];
        #pragma unroll
        for (int r = 0; r < 4; ++r) rs_o[r] = __shfl(rs, lg * 4 + r);
        #pragma unroll
        for (int dt = 0; dt < 8; ++dt)
            #pragma unroll
            for (int r = 0; r < 4; ++r) oacc[dt][r] *= rs_o[r];

        // ---- P -> per-wave LDS (row = q = l15, swizzled chunks) ----
        char* pw = Ps + wv * 2048;
        #pragma unroll
        for (int s = 0; s < 4; ++s)
            #pragma unroll
            for (int r = 0; r < 4; ++r) {
                int key = s * 16 + lg * 4 + r;
                int ch = (key >> 3) ^ (l15 & 7);
                *(unsigned short*)(pw + l15 * 128 + ch * 16 + (key & 7) * 2) = f2bf(p[s][r]);
            }
        asm volatile("" ::: "memory");
        // ---- PV: O += P V  (A = P rows q=l15, B = V cols d=l15) ----
        #pragma unroll
        for (int c = 0; c < 2; ++c) {
            if (j0 + c * 32 <= qmax) {
                bf16x8 pa = *(const bf16x8*)(pw + l15 * 128 + (((c * 4 + lg) ^ (l15 & 7)) << 4));
                #pragma unroll
                for (int dt = 0; dt < 8; ++dt) {
                    int rv = dt * 16 + l15;
                    bf16x8 vf = *(const bf16x8*)(vsb + rv * 128 + (((c * 4 + lg) ^ (rv & 7)) << 4));
                    oacc[dt] = __builtin_amdgcn_mfma_f32_16x16x32_bf16(pa, vf, oacc[dt], 0, 0, 0);
                }
            }
        }
        __syncthreads();   // drains prefetch (issued pre-compute) + guards reuse
        buf ^= 1;
    }

    // ---- depth slots (per-lane q = tq) ----
    float dl[NL];
    #pragma unroll
    for (int sl = 0; sl < NL; ++sl) {
        const float* kd = Dk + sl * DSTRIDE + ((size_t)hk * T_SEQ + tq) * HDIM;
        float a = 0.f;
        #pragma unroll
        for (int c = 0; c < 4; ++c) {
            const float* kc = kd + c * 32 + lg * 8;
            #pragma unroll
            for (int j = 0; j < 8; ++j)
                a = fmaf(bf2f(qf[c][j]), kc[j], a);
        }
        a += __shfl_xor(a, 16);
        a += __shfl_xor(a, 32);
        dl[sl] = a * ATT_SCALE;
    }
    float vm = fmaxf(fmaxf(dl[0], dl[1]), fmaxf(dl[2], dl[3]));
    float mn = fmaxf(m, vm);
    float rsd = __expf(m - mn);
    float pd[NL];
    #pragma unroll
    for (int sl = 0; sl < NL; ++sl) pd[sl] = __expf(dl[sl] - mn);
    l = l * rsd + (pd[0] + pd[1] + pd[2] + pd[3]);
    float linv = 1.f / l;
    float rs_o[4], li_o[4], pdo[NL][4];
    #pragma unroll
    for (int r = 0; r < 4; ++r) {
        rs_o[r] = __shfl(rsd, lg * 4 + r);
        li_o[r] = __shfl(linv, lg * 4 + r);
        #pragma unroll
        for (int sl = 0; sl < NL; ++sl) pdo[sl][r] = __shfl(pd[sl], lg * 4 + r);
    }
    #pragma unroll
    for (int r = 0; r < 4; ++r) {
        int t = q0 + wv * 16 + lg * 4 + r;
        #pragma unroll
        for (int dt = 0; dt < 8; ++dt) {
            const float* vb = Dv + ((size_t)hk * T_SEQ + t) * HDIM + dt * 16 + l15;
            float o = oacc[dt][r] * rs_o[r];
            o = fmaf(pdo[0][r], vb[0], o);
            o = fmaf(pdo[1][r], vb[DSTRIDE], o);
            o = fmaf(pdo[2][r], vb[2 * DSTRIDE], o);
            o = fmaf(pdo[3][r], vb[3 * DSTRIDE], o);
            oacc[dt][r] = o * li_o[r];
        }
    }
    #pragma unroll
    for (int r = 0; r < 4; ++r) {
        unsigned short* orow = AO + (size_t)(q0 + wv * 16 + lg * 4 + r) * DMODEL + hq * HDIM;
        #pragma unroll
        for (int dt = 0; dt < 8; ++dt)
            orow[dt * 16 + l15] = f2bf(oacc[dt][r]);
    }
    #undef STAGE
}

// ---------------------------------------------------------------------------
extern "C" void kernel_launch(void* const* d_in, const int* in_sizes, int n_in,
                              void* d_out, int out_size, void* d_ws, size_t ws_size,
                              hipStream_t stream) {
    const float* x    = (const float*)d_in[0];
    const float* dk   = (const float*)d_in[1];
    const float* dv   = (const float*)d_in[2];
    const float* cosT = (const float*)d_in[3];
    const float* sinT = (const float*)d_in[4];
    const float* Wq   = (const float*)d_in[5];
    const float* Wk   = (const float*)d_in[6];
    const float* Wv   = (const float*)d_in[7];
    const float* Wo   = (const float*)d_in[8];
    float* out = (float*)d_out;

    unsigned short* xb  = (unsigned short*)d_ws;
    unsigned short* Qb  = xb + (size_t)4 * 1024 * 1024;
    unsigned short* Kb  = Qb + (size_t)4 * 1024 * 1024;
    unsigned short* Vt  = Kb + (size_t)2 * 1024 * 1024;
    unsigned short* WTp = Vt + (size_t)2 * 1024 * 1024;
    unsigned short* WoT = WTp + (size_t)8 * 1024 * 1024;
    unsigned short* AOb = xb;   // alias: xb dead after proj GEMM

    cast_f32_bf16<<<dim3(2048), 256, 0, stream>>>(x, xb);
    tcast<<<dim3(32, 32), 256, 0, stream>>>(Wq, WTp, 2048, 2048, 0);
    tcast<<<dim3(32, 16), 256, 0, stream>>>(Wk, WTp, 1024, 2048, 2048);
    tcast<<<dim3(32, 16), 256, 0, stream>>>(Wv, WTp, 1024, 2048, 3072);
    tcast<<<dim3(32, 32), 256, 0, stream>>>(Wo, WoT, 2048, 2048, 0);
    gemm_bt<<<dim3(32, 16), 256, 0, stream>>>(xb, WTp, nullptr, Qb, Kb, Vt, 1, DMODEL);
    rope_bf16<<<dim3(T_SEQ * NHQ * 64 / 256), 256, 0, stream>>>(Qb, cosT, sinT, NHQ);
    rope_bf16<<<dim3(T_SEQ * NHK * 64 / 256), 256, 0, stream>>>(Kb, cosT, sinT, NHK);
    attn_mfma<<<dim3(512), 256, 0, stream>>>(Qb, Kb, Vt, dk, dv, AOb);
    gemm_bt<<<dim3(16, 16), 256, 0, stream>>>(AOb, WoT, out, nullptr, nullptr, nullptr, 0, DMODEL);
}